// Round 13
// baseline (404.160 us; speedup 1.0000x reference)
//
#include <hip/hip_runtime.h>

typedef __attribute__((ext_vector_type(8))) short bf16x8;
typedef __attribute__((ext_vector_type(4))) float f32x4;

#define MFMA16(a,b,c) __builtin_amdgcn_mfma_f32_16x16x32_bf16((a),(b),(c),0,0,0)

__device__ __forceinline__ unsigned short f2bf(float f) {
  unsigned int u = __builtin_bit_cast(unsigned int, f);
  u = (u + 0x7FFFu + ((u >> 16) & 1u)) >> 16;
  return (unsigned short)u;
}
__device__ __forceinline__ float bf2f(unsigned short u) {
  unsigned int v = ((unsigned int)u) << 16;
  return __builtin_bit_cast(float, v);
}
__device__ __forceinline__ unsigned int pack_bf16(float a, float b) {
  return ((unsigned int)f2bf(b) << 16) | (unsigned int)f2bf(a);
}

// ---------------- fused weight transpose fp32 -> bf16, Wt[n][k] = W[k][n], z selects ----------------
__global__ __launch_bounds__(256) void wt_transpose5(
    const float* __restrict__ W0, const float* __restrict__ W1,
    const float* __restrict__ W2, const float* __restrict__ W3,
    const float* __restrict__ W4,
    unsigned short* __restrict__ O0, unsigned short* __restrict__ O1,
    unsigned short* __restrict__ O2, unsigned short* __restrict__ O3,
    unsigned short* __restrict__ O4)
{
  const float* W; unsigned short* Wt;
  switch (blockIdx.z) {
    case 0: W = W0; Wt = O0; break;
    case 1: W = W1; Wt = O1; break;
    case 2: W = W2; Wt = O2; break;
    case 3: W = W3; Wt = O3; break;
    default: W = W4; Wt = O4; break;
  }
  __shared__ unsigned short T[32][33];
  int kb = blockIdx.x * 32, nb = blockIdx.y * 32;
  int tx = threadIdx.x & 31, ty = threadIdx.x >> 5;
  #pragma unroll
  for (int s = 0; s < 4; ++s)
    T[ty + 8*s][tx] = f2bf(W[(kb + ty + 8*s)*512 + nb + tx]);
  __syncthreads();
  #pragma unroll
  for (int s = 0; s < 4; ++s)
    Wt[(nb + ty + 8*s)*512 + kb + tx] = T[tx][ty + 8*s];
}

// ---------------- V transpose bf16 [4096][512] -> [512][4096] ----------------
__global__ __launch_bounds__(256) void v_transpose(const unsigned short* __restrict__ V,
    unsigned short* __restrict__ Vt)
{
  __shared__ unsigned short T[32][33];
  int mb = blockIdx.x * 32, db = blockIdx.y * 32;
  int tx = threadIdx.x & 31, ty = threadIdx.x >> 5;
  #pragma unroll
  for (int s = 0; s < 4; ++s)
    T[ty + 8*s][tx] = V[(mb + ty + 8*s)*512 + db + tx];
  __syncthreads();
  #pragma unroll
  for (int s = 0; s < 4; ++s)
    Vt[(db + ty + 8*s)*4096 + mb + tx] = T[tx][ty + 8*s];
}

// ---------------- fused projection GEMMs: 5 problems in one launch ----------------
// q-segment output pre-multiplied by 512^-0.5 (folds attn scale into projection)
__global__ __launch_bounds__(256) void proj_all(
    const float* __restrict__ x, const float* __restrict__ fine, const float* __restrict__ cmem,
    const unsigned short* __restrict__ WtXK, const unsigned short* __restrict__ WtK,
    const unsigned short* __restrict__ WtV,  const unsigned short* __restrict__ WtCK,
    const unsigned short* __restrict__ WtCV,
    const float* __restrict__ xkb, const float* __restrict__ kb2, const float* __restrict__ vb2,
    const float* __restrict__ ckb, const float* __restrict__ cvb,
    unsigned short* __restrict__ qry, unsigned short* __restrict__ memk,
    unsigned short* __restrict__ memv)
{
  const float* A; const unsigned short* Bt; const float* bias; unsigned short* C;
  int m0;
  int bx = blockIdx.x;
  if (bx < 64) { A = x; Bt = WtXK; bias = xkb; C = qry; m0 = bx * 128; }
  else {
    int seg = (bx - 64) >> 4;
    m0 = ((bx - 64) & 15) * 128;
    switch (seg) {
      case 0:  A = fine; Bt = WtK;  bias = kb2; C = memk;            break;
      case 1:  A = cmem; Bt = WtCK; bias = ckb; C = memk + 2048*512; break;
      case 2:  A = fine; Bt = WtV;  bias = vb2; C = memv;            break;
      default: A = cmem; Bt = WtCV; bias = cvb; C = memv + 2048*512; break;
    }
  }
  const float cs = (bx < 64) ? 0.04419417382415922f : 1.0f;

  __shared__ unsigned short As[128*32];
  __shared__ unsigned short Bs[64*32];
  const int tid = threadIdx.x;
  const int w = tid >> 6, lane = tid & 63;
  const int lr = lane & 15, lg = lane >> 4;
  const int wm = w >> 1, wn = w & 1;
  const int n0 = blockIdx.y * 64;

  f32x4 acc[4][2];
  #pragma unroll
  for (int mt = 0; mt < 4; ++mt)
    #pragma unroll
    for (int nt = 0; nt < 2; ++nt) acc[mt][nt] = (f32x4){0.f,0.f,0.f,0.f};

  const int arow = tid >> 3, af4 = tid & 7;
  const int brow = tid >> 2, bc8 = tid & 3;

  for (int kb = 0; kb < 512; kb += 32) {
    #pragma unroll
    for (int s = 0; s < 4; ++s) {
      const float4 v = *(const float4*)(A + (m0 + arow + 32*s)*512 + kb + af4*4);
      unsigned long long pk = (unsigned long long)f2bf(v.x)
        | ((unsigned long long)f2bf(v.y) << 16)
        | ((unsigned long long)f2bf(v.z) << 32)
        | ((unsigned long long)f2bf(v.w) << 48);
      *(unsigned long long*)&As[(arow + 32*s)*32 + af4*4] = pk;
    }
    *(int4*)&Bs[brow*32 + bc8*8] = *(const int4*)(Bt + (n0 + brow)*512 + kb + bc8*8);
    __syncthreads();
    bf16x8 af[4], bfr[2];
    #pragma unroll
    for (int mt = 0; mt < 4; ++mt)
      af[mt] = *(const bf16x8*)&As[(wm*64 + mt*16 + lr)*32 + lg*8];
    #pragma unroll
    for (int nt = 0; nt < 2; ++nt)
      bfr[nt] = *(const bf16x8*)&Bs[(wn*32 + nt*16 + lr)*32 + lg*8];
    #pragma unroll
    for (int mt = 0; mt < 4; ++mt)
      #pragma unroll
      for (int nt = 0; nt < 2; ++nt)
        acc[mt][nt] = MFMA16(af[mt], bfr[nt], acc[mt][nt]);
    __syncthreads();
  }
  #pragma unroll
  for (int nt = 0; nt < 2; ++nt) {
    int col = n0 + wn*32 + nt*16 + lr;
    float bv = bias[col];
    #pragma unroll
    for (int mt = 0; mt < 4; ++mt) {
      #pragma unroll
      for (int j = 0; j < 4; ++j) {
        int row = m0 + wm*64 + mt*16 + lg*4 + j;
        C[row*512 + col] = f2bf((acc[mt][nt][j] + bv) * cs);
      }
    }
  }
}

// ---------------- flash attention partials: swapped QK^T + d-split PV, V+Q direct from cache ----------------
// NC kv-chunks (grid 128*NC): chunk = bid % NC -> XCD round-robin; ITERS = 4096/NC/32.
// K staged in LDS (shared by 4 waves); V read directly from global vt (L2-resident);
// Q read per-iter from global (L1-resident 16KB/wave tile) -- frees the 64-reg qa array
// so the allocator can fit 3 waves/SIMD (launch_bounds min-waves=3 -> <=170 regs).
// Schedule per iter (2 barriers):
//   QK(own q-tile, Ks x Q-global) -> softmax(per-lane) -> write Pl/Fl/Tf
//   |A|  STAGE_K(it+1); rescale o via Tf/Fl; pa[4] from Pl; PV (V global, d-slice w)
//   |B|  (Pl consumed; K(it+1) drained under rescale+PV window)
template<int NC>
__global__ __launch_bounds__(256, 3) void attn_kernel(
    const unsigned short* __restrict__ q,   // [8192][512] bf16, pre-scaled by 512^-0.5
    const unsigned short* __restrict__ mk,  // [4096][512] bf16
    const unsigned short* __restrict__ vt,  // [512][4096] bf16
    unsigned short* __restrict__ opart,     // [NC][8192][512] bf16, unnormalized
    float* __restrict__ mpart,              // [NC][8192]
    float* __restrict__ lpart)              // [NC][8192]
{
  constexpr int CK = 4096 / NC;       // keys per chunk
  constexpr int ITERS = CK / 32;

  __shared__ unsigned short Ks[32*520];     // rows 1040 B (16 B pad between gl_lds rows)
  __shared__ unsigned short Pl[64*32];      // P[q][kv] bf16, rows 64 B
  __shared__ float Fl[64];                  // per-q-row rescale factors
  __shared__ unsigned int Tf[4];            // per-q-tile trigger flags

  const int tid = threadIdx.x;
  const int w = tid >> 6, lane = tid & 63;
  const int lr = lane & 15, lg = lane >> 4;
  const int bid = blockIdx.x;
  const int chunk = bid & (NC - 1);
  const int qb = bid / NC;
  const int q0blk = qb * 64;
  const int kvbase = chunk * CK;

  // Q base for wave's own q-tile row (q0blk + w*16 + lr), slice lg*8; frag ks at +ks*32
  const unsigned short* qgp = q + (size_t)(q0blk + w*16 + lr) * 512 + lg*8;

  // O accumulators: o[qt*8+dt] = O[q0blk + qt*16 + 4lg+j][w*128 + dt*16 + lr]
  f32x4 o[32];
  #pragma unroll
  for (int nt = 0; nt < 32; ++nt) o[nt] = (f32x4){0.f,0.f,0.f,0.f};
  float m = -1e30f, l = 0.f;   // per-lane, for q-row q0blk + 16w + lr (replicated over lg)

  // per-lane global V base: row (w*128 + lr), col kvbase + lg*8
  const unsigned short* vgp = vt + (size_t)(w*128 + lr) * 4096 + kvbase + lg*8;

  #define STAGE_K(IT) do {                                                        \
    int kv0_ = kvbase + (IT) * 32;                                                \
    _Pragma("unroll")                                                             \
    for (int i_ = 0; i_ < 8; ++i_) {                                              \
      int r_ = w * 8 + i_;                                                        \
      __builtin_amdgcn_global_load_lds(                                           \
        (const __attribute__((address_space(1))) unsigned int*)                   \
          (mk + (kv0_ + r_)*512 + lane*8),                                        \
        (__attribute__((address_space(3))) unsigned int*)(&Ks[r_*520]), 16, 0, 0);\
    }                                                                             \
  } while (0)

  STAGE_K(0);
  __syncthreads();   // drains prologue staging

  const unsigned short* k0p = &Ks[lr * 520];          // K rows kv0..15 (A-frag)
  const unsigned short* k1p = &Ks[(lr + 16) * 520];   // K rows kv16..31

  for (int it = 0; it < ITERS; ++it) {
    // ---- QK^T swapped: T = K.Q^T for own q-tile; Q streamed from L1 ----
    f32x4 t0a = (f32x4){0.f,0.f,0.f,0.f}, t0b = (f32x4){0.f,0.f,0.f,0.f};
    f32x4 t1a = (f32x4){0.f,0.f,0.f,0.f}, t1b = (f32x4){0.f,0.f,0.f,0.f};
    #pragma unroll
    for (int ks = 0; ks < 8; ++ks) {
      bf16x8 qf  = *(const bf16x8*)(qgp + ks*32);
      bf16x8 kb0 = *(const bf16x8*)(k0p + ks*32 + lg*8);
      bf16x8 kb1 = *(const bf16x8*)(k1p + ks*32 + lg*8);
      t0a = MFMA16(kb0, qf, t0a);
      t1a = MFMA16(kb1, qf, t1a);
      bf16x8 qfb  = *(const bf16x8*)(qgp + (ks+8)*32);
      bf16x8 kb0b = *(const bf16x8*)(k0p + (ks+8)*32 + lg*8);
      bf16x8 kb1b = *(const bf16x8*)(k1p + (ks+8)*32 + lg*8);
      t0b = MFMA16(kb0b, qfb, t0b);
      t1b = MFMA16(kb1b, qfb, t1b);
    }

    float t0[4], t1[4];
    #pragma unroll
    for (int j = 0; j < 4; ++j) { t0[j] = t0a[j] + t0b[j]; t1[j] = t1a[j] + t1b[j]; }

    // ---- per-lane softmax for q = q0blk + 16w + lr (pre-barrier) ----
    float pm = fmaxf(fmaxf(fmaxf(t0[0], t0[1]), fmaxf(t0[2], t0[3])),
                     fmaxf(fmaxf(t1[0], t1[1]), fmaxf(t1[2], t1[3])));
    pm = fmaxf(pm, __shfl_xor(pm, 16));
    pm = fmaxf(pm, __shfl_xor(pm, 32));

    bool trig = !__all(pm <= m + 8.f);
    if (trig) {
      float mn = fmaxf(m, pm);
      float fl = __expf(m - mn);
      l *= fl;
      m = mn;
      if (lg == 0) Fl[w*16 + lr] = fl;   // factors for this q-tile
    }
    if (lane == 0) Tf[w] = trig ? 1u : 0u;

    float p0[4], p1[4];
    #pragma unroll
    for (int j = 0; j < 4; ++j) {
      p0[j] = __expf(t0[j] - m);
      p1[j] = __expf(t1[j] - m);
    }
    float rs = ((p0[0] + p0[1]) + (p0[2] + p0[3]))
             + ((p1[0] + p1[1]) + (p1[2] + p1[3]));
    rs += __shfl_xor(rs, 16);
    rs += __shfl_xor(rs, 32);
    l += rs;

    // ---- pack P and write to Pl[q][kv] (rows 64 B) ----
    {
      unsigned int u0 = pack_bf16(p0[0], p0[1]);   // kv 4lg+0,1
      unsigned int u1 = pack_bf16(p0[2], p0[3]);   // kv 4lg+2,3
      unsigned int u2 = pack_bf16(p1[0], p1[1]);   // kv 16+4lg+0,1
      unsigned int u3 = pack_bf16(p1[2], p1[3]);   // kv 16+4lg+2,3
      *(uint2*)&Pl[(w*16 + lr)*32 + lg*4]      = make_uint2(u0, u1);
      *(uint2*)&Pl[(w*16 + lr)*32 + 16 + lg*4] = make_uint2(u2, u3);
    }
    __syncthreads();  // A: Ks consumed; Pl/Fl/Tf visible

    if (it + 1 < ITERS) STAGE_K(it + 1);   // refill K; drains at B (under rescale+PV)

    // ---- cross-tile o rescale (block-uniform per q-tile) ----
    unsigned int tf0 = Tf[0], tf1 = Tf[1], tf2 = Tf[2], tf3 = Tf[3];
    if (tf0 | tf1 | tf2 | tf3) {
      #pragma unroll
      for (int qt = 0; qt < 4; ++qt) {
        unsigned int tfq = (qt == 0) ? tf0 : (qt == 1) ? tf1 : (qt == 2) ? tf2 : tf3;
        if (tfq) {
          f32x4 fq = *(const f32x4*)&Fl[qt*16 + lg*4];
          #pragma unroll
          for (int dt = 0; dt < 8; ++dt) {
            o[qt*8 + dt][0] *= fq[0]; o[qt*8 + dt][1] *= fq[1];
            o[qt*8 + dt][2] *= fq[2]; o[qt*8 + dt][3] *= fq[3];
          }
        }
      }
    }

    // ---- PV d-split: O[64 q x 128-d slice] += P[64 x 32] @ V[32 x slice], V from L2 ----
    bf16x8 pa[4];
    #pragma unroll
    for (int qt = 0; qt < 4; ++qt)
      pa[qt] = *(const bf16x8*)&Pl[(qt*16 + lr)*32 + lg*8];
    const unsigned short* vit = vgp + it*32;
    #pragma unroll
    for (int dh = 0; dh < 2; ++dh) {
      bf16x8 vb[4];
      #pragma unroll
      for (int dt = 0; dt < 4; ++dt)
        vb[dt] = *(const bf16x8*)(vit + (size_t)(dh*4 + dt)*16*4096);
      #pragma unroll
      for (int qt = 0; qt < 4; ++qt) {
        #pragma unroll
        for (int dt = 0; dt < 4; ++dt)
          o[qt*8 + dh*4 + dt] = MFMA16(pa[qt], vb[dt], o[qt*8 + dh*4 + dt]);
      }
    }
    __syncthreads();  // B: Pl consumed; K(it+1) drained
  }

  // ---- store unnormalized partial + m/l ----
  unsigned short* ob = opart + (size_t)chunk * 8192 * 512;
  #pragma unroll
  for (int qt = 0; qt < 4; ++qt) {
    #pragma unroll
    for (int dt = 0; dt < 8; ++dt) {
      #pragma unroll
      for (int j = 0; j < 4; ++j) {
        int row = q0blk + qt*16 + lg*4 + j;
        int col = w*128 + dt*16 + lr;
        ob[row*512 + col] = f2bf(o[qt*8 + dt][j]);
      }
    }
  }
  if (lane < 16) {
    mpart[chunk*8192 + q0blk + w*16 + lane] = m;
    lpart[chunk*8192 + q0blk + w*16 + lane] = l;
  }
  #undef STAGE_K
}

// ---------------- combine partials (16B-vectorized opart reads) ----------------
template<int NC>
__global__ __launch_bounds__(256) void attn_combine(
    const unsigned short* __restrict__ opart, const float* __restrict__ mpart,
    const float* __restrict__ lpart, const float* __restrict__ x,
    float* __restrict__ out)
{
  int row = blockIdx.x * 4 + (threadIdx.x >> 6);
  int t = threadIdx.x & 63;
  int d0 = t * 8;
  float mc[NC], lc[NC];
  #pragma unroll
  for (int c = 0; c < NC; ++c) { mc[c] = mpart[c*8192 + row]; lc[c] = lpart[c*8192 + row]; }
  float M = mc[0];
  #pragma unroll
  for (int c = 1; c < NC; ++c) M = fmaxf(M, mc[c]);
  float wc[NC], denom = 0.f;
  #pragma unroll
  for (int c = 0; c < NC; ++c) { wc[c] = __expf(mc[c] - M); denom += wc[c] * lc[c]; }
  float inv = 1.0f / denom;
  float acc[8] = {0.f,0.f,0.f,0.f,0.f,0.f,0.f,0.f};
  const unsigned short* base = opart + (size_t)row*512 + d0;
  #pragma unroll
  for (int c = 0; c < NC; ++c) {
    int4 v = *(const int4*)(base + (size_t)c * 8192 * 512);
    const unsigned short* u = (const unsigned short*)&v;
    #pragma unroll
    for (int e = 0; e < 8; ++e) acc[e] += wc[c] * bf2f(u[e]);
  }
  float4 xv0 = *(const float4*)(x + row*512 + d0);
  float4 xv1 = *(const float4*)(x + row*512 + d0 + 4);
  float4 o0, o1;
  o0.x = xv0.x + acc[0]*inv; o0.y = xv0.y + acc[1]*inv;
  o0.z = xv0.z + acc[2]*inv; o0.w = xv0.w + acc[3]*inv;
  o1.x = xv1.x + acc[4]*inv; o1.y = xv1.y + acc[5]*inv;
  o1.z = xv1.z + acc[6]*inv; o1.w = xv1.w + acc[7]*inv;
  *(float4*)(out + row*512 + d0)     = o0;
  *(float4*)(out + row*512 + d0 + 4) = o1;
}

// ---------------- recon path (fp32 exact) ----------------
__global__ __launch_bounds__(256) void compress_pool(const float* __restrict__ fine,
    const float* __restrict__ cq, float* __restrict__ pooled, float* __restrict__ loss)
{
  if (blockIdx.x == 0 && threadIdx.x == 0) *loss = 0.f;   // fused zero (interp runs later)
  int l = blockIdx.x;
  int t = threadIdx.x;
  const float* c0 = fine + (2*l)*512;
  const float* c1 = c0 + 512;
  float q0 = cq[t], q1 = cq[t+256];
  float a0 = q0*c0[t] + q1*c0[t+256];
  float a1 = q0*c1[t] + q1*c1[t+256];
  #pragma unroll
  for (int m = 1; m < 64; m <<= 1) { a0 += __shfl_xor(a0, m); a1 += __shfl_xor(a1, m); }
  __shared__ float r0[4], r1[4];
  int w = t >> 6;
  if ((t & 63) == 0) { r0[w] = a0; r1[w] = a1; }
  __syncthreads();
  const float sc = 0.04419417382415922f;
  float g0 = (r0[0]+r0[1]+r0[2]+r0[3]) * sc;
  float g1 = (r1[0]+r1[1]+r1[2]+r1[3]) * sc;
  float mx = fmaxf(g0, g1);
  float e0 = __expf(g0-mx), e1 = __expf(g1-mx);
  float inv = 1.0f/(e0+e1);
  float w0 = e0*inv, w1 = e1*inv;
  pooled[l*512 + t]       = w0*c0[t]     + w1*c1[t];
  pooled[l*512 + t + 256] = w0*c0[t+256] + w1*c1[t+256];
}

__global__ __launch_bounds__(256) void comp_gemm(const float* __restrict__ P,
    const float* __restrict__ W, const float* __restrict__ b, float* __restrict__ out)
{
  int gid = blockIdx.x * 256 + threadIdx.x;
  int m = gid >> 9, n = gid & 511;
  const float* a = P + m * 512;
  float acc = b[n];
  #pragma unroll 8
  for (int k = 0; k < 512; ++k) acc += a[k] * W[k*512 + n];
  out[gid] = acc;
}

__global__ __launch_bounds__(256) void interp_loss(const float* __restrict__ comp,
    const float* __restrict__ fine, float* __restrict__ loss)
{
  float acc = 0.f;
  #pragma unroll
  for (int s = 0; s < 4; ++s) {
    int e = blockIdx.x*1024 + s*256 + threadIdx.x;
    int i = e >> 9, d = e & 511;
    float src = fminf(fmaxf((i + 0.5f)*0.5f - 0.5f, 0.f), 255.f);
    int i0 = (int)src;
    int i1 = min(i0 + 1, 255);
    float fr = src - (float)i0;
    float dec = (1.f - fr)*comp[i0*512 + d] + fr*comp[i1*512 + d];
    float df = dec - fine[e];
    acc += df*df;
  }
  #pragma unroll
  for (int m = 1; m < 64; m <<= 1) acc += __shfl_xor(acc, m);
  __shared__ float r[4];
  int w = threadIdx.x >> 6;
  if ((threadIdx.x & 63) == 0) r[w] = acc;
  __syncthreads();
  if (threadIdx.x == 0)
    atomicAdd(loss, (r[0]+r[1]+r[2]+r[3]) * (1.0f/262144.0f));
}

extern "C" void kernel_launch(void* const* d_in, const int* in_sizes, int n_in,
                              void* d_out, int out_size, void* d_ws, size_t ws_size,
                              hipStream_t stream) {
  const float* x     = (const float*)d_in[0];
  const float* fine  = (const float*)d_in[1];
  const float* cmem  = (const float*)d_in[2];
  const float* cq    = (const float*)d_in[3];
  const float* compW = (const float*)d_in[4];
  const float* compb = (const float*)d_in[5];
  const float* kW    = (const float*)d_in[6];
  const float* kb_   = (const float*)d_in[7];
  const float* vW    = (const float*)d_in[8];
  const float* vb_   = (const float*)d_in[9];
  const float* xkW   = (const float*)d_in[10];
  const float* xkb   = (const float*)d_in[11];
  const float* ckW   = (const float*)d_in[12];
  const float* ckb   = (const float*)d_in[13];
  const float* cvW   = (const float*)d_in[14];
  const float* cvb   = (const float*)d_in[15];

  char* ws = (char*)d_ws;
  const size_t WT = 512*512*2;              // 512 KB per transposed weight
  unsigned short* WtK  = (unsigned short*)(ws + 0*WT);
  unsigned short* WtV  = (unsigned short*)(ws + 1*WT);
  unsigned short* WtCK = (unsigned short*)(ws + 2*WT);
  unsigned short* WtCV = (unsigned short*)(ws + 3*WT);
  unsigned short* WtXK = (unsigned short*)(ws + 4*WT);
  char* base = ws + 5*WT;
  unsigned short* memk = (unsigned short*)(base);                       // 4 MB
  unsigned short* memv = (unsigned short*)(base + (4u<<20));            // 4 MB
  unsigned short* vt   = (unsigned short*)(base + (8u<<20));            // 4 MB
  unsigned short* qry  = (unsigned short*)(base + (12u<<20));           // 8 MB
  float* pooled        = (float*)(base + (20u<<20));                    // 512 KB
  float* comp          = (float*)(base + (20u<<20) + (512u<<10));       // 512 KB
  unsigned short* opart= (unsigned short*)(base + (21u<<20));           // NC*8 MB

  float* out  = (float*)d_out;
  float* loss = out + 8192*512;

  // choose kv-split by available workspace (deterministic: ws_size is fixed)
  const size_t fixed = 5*WT + (21ull<<20);
  const size_t need8 = fixed + 8ull*(8ull<<20) + 2ull*8*8192*4 + (1ull<<20);
  const bool use8 = (ws_size >= need8);
  const int NCv = use8 ? 8 : 4;
  float* mpart = (float*)(base + (21u<<20) + (size_t)NCv*(8u<<20));
  float* lpart = mpart + (size_t)NCv*8192;

  wt_transpose5<<<dim3(16,16,5), 256, 0, stream>>>(kW, vW, ckW, cvW, xkW,
                                                   WtK, WtV, WtCK, WtCV, WtXK);

  proj_all<<<dim3(128,8), 256, 0, stream>>>(x, fine, cmem,
      WtXK, WtK, WtV, WtCK, WtCV,
      xkb, kb_, vb_, ckb, cvb,
      qry, memk, memv);

  v_transpose<<<dim3(128,16), 256, 0, stream>>>(memv, vt);

  if (use8) {
    attn_kernel<8><<<1024, 256, 0, stream>>>(qry, memk, vt, opart, mpart, lpart);
    attn_combine<8><<<2048, 256, 0, stream>>>(opart, mpart, lpart, x, out);
  } else {
    attn_kernel<4><<<512, 256, 0, stream>>>(qry, memk, vt, opart, mpart, lpart);
    attn_combine<4><<<2048, 256, 0, stream>>>(opart, mpart, lpart, x, out);
  }

  compress_pool<<<256, 256, 0, stream>>>(fine, cq, pooled, loss);
  comp_gemm<<<512, 256, 0, stream>>>(pooled, compW, compb, comp);
  interp_loss<<<256, 256, 0, stream>>>(comp, fine, loss);
}

// Round 14
// 184.618 us; speedup vs baseline: 2.1892x; 2.1892x over previous
//
#include <hip/hip_runtime.h>

typedef __attribute__((ext_vector_type(8))) short bf16x8;
typedef __attribute__((ext_vector_type(4))) float f32x4;

#define MFMA16(a,b,c) __builtin_amdgcn_mfma_f32_16x16x32_bf16((a),(b),(c),0,0,0)

__device__ __forceinline__ unsigned short f2bf(float f) {
  unsigned int u = __builtin_bit_cast(unsigned int, f);
  u = (u + 0x7FFFu + ((u >> 16) & 1u)) >> 16;
  return (unsigned short)u;
}
__device__ __forceinline__ float bf2f(unsigned short u) {
  unsigned int v = ((unsigned int)u) << 16;
  return __builtin_bit_cast(float, v);
}
__device__ __forceinline__ unsigned int pack_bf16(float a, float b) {
  return ((unsigned int)f2bf(b) << 16) | (unsigned int)f2bf(a);
}

// ---------------- fused weight transpose fp32 -> bf16, Wt[n][k] = W[k][n], z selects ----------------
__global__ __launch_bounds__(256) void wt_transpose5(
    const float* __restrict__ W0, const float* __restrict__ W1,
    const float* __restrict__ W2, const float* __restrict__ W3,
    const float* __restrict__ W4,
    unsigned short* __restrict__ O0, unsigned short* __restrict__ O1,
    unsigned short* __restrict__ O2, unsigned short* __restrict__ O3,
    unsigned short* __restrict__ O4)
{
  const float* W; unsigned short* Wt;
  switch (blockIdx.z) {
    case 0: W = W0; Wt = O0; break;
    case 1: W = W1; Wt = O1; break;
    case 2: W = W2; Wt = O2; break;
    case 3: W = W3; Wt = O3; break;
    default: W = W4; Wt = O4; break;
  }
  __shared__ unsigned short T[32][33];
  int kb = blockIdx.x * 32, nb = blockIdx.y * 32;
  int tx = threadIdx.x & 31, ty = threadIdx.x >> 5;
  #pragma unroll
  for (int s = 0; s < 4; ++s)
    T[ty + 8*s][tx] = f2bf(W[(kb + ty + 8*s)*512 + nb + tx]);
  __syncthreads();
  #pragma unroll
  for (int s = 0; s < 4; ++s)
    Wt[(nb + ty + 8*s)*512 + kb + tx] = T[tx][ty + 8*s];
}

// ---------------- V transpose bf16 [4096][512] -> [512][4096] ----------------
__global__ __launch_bounds__(256) void v_transpose(const unsigned short* __restrict__ V,
    unsigned short* __restrict__ Vt)
{
  __shared__ unsigned short T[32][33];
  int mb = blockIdx.x * 32, db = blockIdx.y * 32;
  int tx = threadIdx.x & 31, ty = threadIdx.x >> 5;
  #pragma unroll
  for (int s = 0; s < 4; ++s)
    T[ty + 8*s][tx] = V[(mb + ty + 8*s)*512 + db + tx];
  __syncthreads();
  #pragma unroll
  for (int s = 0; s < 4; ++s)
    Vt[(db + ty + 8*s)*4096 + mb + tx] = T[tx][ty + 8*s];
}

// ---------------- fused projection GEMMs: 5 problems in one launch ----------------
// q-segment output pre-multiplied by 512^-0.5 (folds attn scale into projection)
__global__ __launch_bounds__(256) void proj_all(
    const float* __restrict__ x, const float* __restrict__ fine, const float* __restrict__ cmem,
    const unsigned short* __restrict__ WtXK, const unsigned short* __restrict__ WtK,
    const unsigned short* __restrict__ WtV,  const unsigned short* __restrict__ WtCK,
    const unsigned short* __restrict__ WtCV,
    const float* __restrict__ xkb, const float* __restrict__ kb2, const float* __restrict__ vb2,
    const float* __restrict__ ckb, const float* __restrict__ cvb,
    unsigned short* __restrict__ qry, unsigned short* __restrict__ memk,
    unsigned short* __restrict__ memv)
{
  const float* A; const unsigned short* Bt; const float* bias; unsigned short* C;
  int m0;
  int bx = blockIdx.x;
  if (bx < 64) { A = x; Bt = WtXK; bias = xkb; C = qry; m0 = bx * 128; }
  else {
    int seg = (bx - 64) >> 4;
    m0 = ((bx - 64) & 15) * 128;
    switch (seg) {
      case 0:  A = fine; Bt = WtK;  bias = kb2; C = memk;            break;
      case 1:  A = cmem; Bt = WtCK; bias = ckb; C = memk + 2048*512; break;
      case 2:  A = fine; Bt = WtV;  bias = vb2; C = memv;            break;
      default: A = cmem; Bt = WtCV; bias = cvb; C = memv + 2048*512; break;
    }
  }
  const float cs = (bx < 64) ? 0.04419417382415922f : 1.0f;

  __shared__ unsigned short As[128*32];
  __shared__ unsigned short Bs[64*32];
  const int tid = threadIdx.x;
  const int w = tid >> 6, lane = tid & 63;
  const int lr = lane & 15, lg = lane >> 4;
  const int wm = w >> 1, wn = w & 1;
  const int n0 = blockIdx.y * 64;

  f32x4 acc[4][2];
  #pragma unroll
  for (int mt = 0; mt < 4; ++mt)
    #pragma unroll
    for (int nt = 0; nt < 2; ++nt) acc[mt][nt] = (f32x4){0.f,0.f,0.f,0.f};

  const int arow = tid >> 3, af4 = tid & 7;
  const int brow = tid >> 2, bc8 = tid & 3;

  for (int kb = 0; kb < 512; kb += 32) {
    #pragma unroll
    for (int s = 0; s < 4; ++s) {
      const float4 v = *(const float4*)(A + (m0 + arow + 32*s)*512 + kb + af4*4);
      unsigned long long pk = (unsigned long long)f2bf(v.x)
        | ((unsigned long long)f2bf(v.y) << 16)
        | ((unsigned long long)f2bf(v.z) << 32)
        | ((unsigned long long)f2bf(v.w) << 48);
      *(unsigned long long*)&As[(arow + 32*s)*32 + af4*4] = pk;
    }
    *(int4*)&Bs[brow*32 + bc8*8] = *(const int4*)(Bt + (n0 + brow)*512 + kb + bc8*8);
    __syncthreads();
    bf16x8 af[4], bfr[2];
    #pragma unroll
    for (int mt = 0; mt < 4; ++mt)
      af[mt] = *(const bf16x8*)&As[(wm*64 + mt*16 + lr)*32 + lg*8];
    #pragma unroll
    for (int nt = 0; nt < 2; ++nt)
      bfr[nt] = *(const bf16x8*)&Bs[(wn*32 + nt*16 + lr)*32 + lg*8];
    #pragma unroll
    for (int mt = 0; mt < 4; ++mt)
      #pragma unroll
      for (int nt = 0; nt < 2; ++nt)
        acc[mt][nt] = MFMA16(af[mt], bfr[nt], acc[mt][nt]);
    __syncthreads();
  }
  #pragma unroll
  for (int nt = 0; nt < 2; ++nt) {
    int col = n0 + wn*32 + nt*16 + lr;
    float bv = bias[col];
    #pragma unroll
    for (int mt = 0; mt < 4; ++mt) {
      #pragma unroll
      for (int j = 0; j < 4; ++j) {
        int row = m0 + wm*64 + mt*16 + lg*4 + j;
        C[row*512 + col] = f2bf((acc[mt][nt][j] + bv) * cs);
      }
    }
  }
}

// ---------------- flash attention partials: swapped QK^T, KVBLK=64, d-split PV ----------------
// NC=4 kv-chunks (grid 512): chunk = bid&3 -> XCD round-robin; ITERS = 1024/64 = 16.
// KVBLK=64 halves barrier crossings vs KVBLK=32 (2 per 64 kv instead of 4).
// K staged in LDS (shared by 4 waves); V direct from global (L2); Q direct from global
// (L2/L1-resident, same addrs every iter) to keep total regs <= 256 at 2 waves/SIMD.
// Schedule per iter (2 barriers):
//   QK(4 kv-row-groups x 16 ks) -> softmax(16 scores/lane) -> write Pl/Fl/Tf
//   |A|  STAGE_K(it+1); rescale o; PV (2 kv-halves x 2 d-halves, V global)
//   |B|  (Pl consumed; K(it+1) drained under rescale+PV window)
template<int NC>
__global__ __launch_bounds__(256, 2) void attn_kernel(
    const unsigned short* __restrict__ q,   // [8192][512] bf16, pre-scaled by 512^-0.5
    const unsigned short* __restrict__ mk,  // [4096][512] bf16
    const unsigned short* __restrict__ vt,  // [512][4096] bf16
    unsigned short* __restrict__ opart,     // [NC][8192][512] bf16, unnormalized
    float* __restrict__ mpart,              // [NC][8192]
    float* __restrict__ lpart)              // [NC][8192]
{
  constexpr int CK = 4096 / NC;       // keys per chunk (1024)
  constexpr int ITERS = CK / 64;      // 16
  constexpr int PLW = 68;             // Pl row stride (136 B -> 2 lanes/quad on read+write)

  __shared__ unsigned short Ks[64*520];     // 65 KB; rows 1040 B (16 B pad per gl_lds row)
  __shared__ unsigned short Pl[64*PLW];     // 8.5 KB, P[q][kv]
  __shared__ float Fl[64];                  // per-q-row rescale factors
  __shared__ unsigned int Tf[4];            // per-q-tile trigger flags

  const int tid = threadIdx.x;
  const int w = tid >> 6, lane = tid & 63;
  const int lr = lane & 15, lg = lane >> 4;
  const int bid = blockIdx.x;
  const int chunk = bid & (NC - 1);
  const int qb = bid / NC;
  const int q0blk = qb * 64;
  const int kvbase = chunk * CK;

  // Q base for wave's q-tile row (q0blk + w*16 + lr), slice lg*8; frag ks at +ks*32
  const unsigned short* qgp = q + (size_t)(q0blk + w*16 + lr) * 512 + lg*8;

  // O accumulators: o[qt*8+dt] = O[q0blk + qt*16 + 4lg+j][w*128 + dt*16 + lr]
  f32x4 o[32];
  #pragma unroll
  for (int nt = 0; nt < 32; ++nt) o[nt] = (f32x4){0.f,0.f,0.f,0.f};
  float m = -1e30f, l = 0.f;   // per-lane, q-row q0blk + 16w + lr (replicated over lg)

  // per-lane global V base: row (w*128 + lr), col kvbase + lg*8
  const unsigned short* vgp = vt + (size_t)(w*128 + lr) * 4096 + kvbase + lg*8;

  #define STAGE_K(IT) do {                                                        \
    int kv0_ = kvbase + (IT) * 64;                                                \
    _Pragma("unroll")                                                             \
    for (int i_ = 0; i_ < 16; ++i_) {                                             \
      int r_ = w * 16 + i_;                                                       \
      __builtin_amdgcn_global_load_lds(                                           \
        (const __attribute__((address_space(1))) unsigned int*)                   \
          (mk + (kv0_ + r_)*512 + lane*8),                                        \
        (__attribute__((address_space(3))) unsigned int*)(&Ks[r_*520]), 16, 0, 0);\
    }                                                                             \
  } while (0)

  STAGE_K(0);
  __syncthreads();   // drains prologue staging

  const unsigned short* kp = &Ks[lr * 520];   // group g at +g*16 rows

  for (int it = 0; it < ITERS; ++it) {
    // ---- QK^T swapped: T = K.Q^T, 4 kv-row-groups (independent chains), Q from cache ----
    f32x4 t0 = (f32x4){0.f,0.f,0.f,0.f}, t1 = (f32x4){0.f,0.f,0.f,0.f};
    f32x4 t2 = (f32x4){0.f,0.f,0.f,0.f}, t3 = (f32x4){0.f,0.f,0.f,0.f};
    #pragma unroll
    for (int ks = 0; ks < 16; ++ks) {
      bf16x8 qf  = *(const bf16x8*)(qgp + ks*32);
      bf16x8 kb0 = *(const bf16x8*)(kp + ks*32 + lg*8);
      bf16x8 kb1 = *(const bf16x8*)(kp + 16*520 + ks*32 + lg*8);
      bf16x8 kb2 = *(const bf16x8*)(kp + 32*520 + ks*32 + lg*8);
      bf16x8 kb3 = *(const bf16x8*)(kp + 48*520 + ks*32 + lg*8);
      t0 = MFMA16(kb0, qf, t0);
      t1 = MFMA16(kb1, qf, t1);
      t2 = MFMA16(kb2, qf, t2);
      t3 = MFMA16(kb3, qf, t3);
    }
    // lane (lr,lg): t{g}[j] = S[q=q0blk+16w+lr][kv = it*64 + g*16 + 4lg + j]

    // ---- per-lane softmax over 16 scores (pre-barrier) ----
    float pm = fmaxf(fmaxf(fmaxf(t0[0], t0[1]), fmaxf(t0[2], t0[3])),
                     fmaxf(fmaxf(t1[0], t1[1]), fmaxf(t1[2], t1[3])));
    pm = fmaxf(pm, fmaxf(fmaxf(fmaxf(t2[0], t2[1]), fmaxf(t2[2], t2[3])),
                         fmaxf(fmaxf(t3[0], t3[1]), fmaxf(t3[2], t3[3]))));
    pm = fmaxf(pm, __shfl_xor(pm, 16));
    pm = fmaxf(pm, __shfl_xor(pm, 32));

    bool trig = !__all(pm <= m + 8.f);
    if (trig) {
      float mn = fmaxf(m, pm);
      float fl = __expf(m - mn);
      l *= fl;
      m = mn;
      if (lg == 0) Fl[w*16 + lr] = fl;
    }
    if (lane == 0) Tf[w] = trig ? 1u : 0u;

    float p0[4], p1[4], p2[4], p3[4];
    #pragma unroll
    for (int j = 0; j < 4; ++j) {
      p0[j] = __expf(t0[j] - m);
      p1[j] = __expf(t1[j] - m);
      p2[j] = __expf(t2[j] - m);
      p3[j] = __expf(t3[j] - m);
    }
    float rs = ((p0[0]+p0[1]) + (p0[2]+p0[3])) + ((p1[0]+p1[1]) + (p1[2]+p1[3]))
             + ((p2[0]+p2[1]) + (p2[2]+p2[3])) + ((p3[0]+p3[1]) + (p3[2]+p3[3]));
    rs += __shfl_xor(rs, 16);
    rs += __shfl_xor(rs, 32);
    l += rs;

    // ---- pack P and write Pl[q][kv] (rows PLW=68 elems; 2-way bank-aliasing = free) ----
    {
      unsigned short* pr = &Pl[(w*16 + lr)*PLW + lg*4];
      *(uint2*)(pr)      = make_uint2(pack_bf16(p0[0], p0[1]), pack_bf16(p0[2], p0[3]));
      *(uint2*)(pr + 16) = make_uint2(pack_bf16(p1[0], p1[1]), pack_bf16(p1[2], p1[3]));
      *(uint2*)(pr + 32) = make_uint2(pack_bf16(p2[0], p2[1]), pack_bf16(p2[2], p2[3]));
      *(uint2*)(pr + 48) = make_uint2(pack_bf16(p3[0], p3[1]), pack_bf16(p3[2], p3[3]));
    }
    __syncthreads();  // A: Ks consumed; Pl/Fl/Tf visible

    if (it + 1 < ITERS) STAGE_K(it + 1);   // refill K; drains at B (under rescale+PV)

    // ---- cross-tile o rescale (block-uniform per q-tile) ----
    unsigned int tf0 = Tf[0], tf1 = Tf[1], tf2 = Tf[2], tf3 = Tf[3];
    if (tf0 | tf1 | tf2 | tf3) {
      #pragma unroll
      for (int qt = 0; qt < 4; ++qt) {
        unsigned int tfq = (qt == 0) ? tf0 : (qt == 1) ? tf1 : (qt == 2) ? tf2 : tf3;
        if (tfq) {
          f32x4 fq = *(const f32x4*)&Fl[qt*16 + lg*4];
          #pragma unroll
          for (int dt = 0; dt < 8; ++dt) {
            o[qt*8 + dt][0] *= fq[0]; o[qt*8 + dt][1] *= fq[1];
            o[qt*8 + dt][2] *= fq[2]; o[qt*8 + dt][3] *= fq[3];
          }
        }
      }
    }

    // ---- PV d-split: O[64 q x 128-d slice] += P[64 x 64] @ V[64 x slice], V from L2 ----
    const unsigned short* vit = vgp + it*64;
    #pragma unroll
    for (int kvh = 0; kvh < 2; ++kvh) {
      bf16x8 pa[4];
      #pragma unroll
      for (int qt = 0; qt < 4; ++qt)
        pa[qt] = *(const bf16x8*)&Pl[(qt*16 + lr)*PLW + kvh*32 + lg*8];
      #pragma unroll
      for (int dh = 0; dh < 2; ++dh) {
        bf16x8 vb[4];
        #pragma unroll
        for (int dt = 0; dt < 4; ++dt)
          vb[dt] = *(const bf16x8*)(vit + kvh*32 + (size_t)(dh*4 + dt)*16*4096);
        #pragma unroll
        for (int qt = 0; qt < 4; ++qt) {
          #pragma unroll
          for (int dt = 0; dt < 4; ++dt)
            o[qt*8 + dh*4 + dt] = MFMA16(pa[qt], vb[dt], o[qt*8 + dh*4 + dt]);
        }
      }
    }
    __syncthreads();  // B: Pl consumed; K(it+1) drained
  }

  // ---- store unnormalized partial + m/l ----
  unsigned short* ob = opart + (size_t)chunk * 8192 * 512;
  #pragma unroll
  for (int qt = 0; qt < 4; ++qt) {
    #pragma unroll
    for (int dt = 0; dt < 8; ++dt) {
      #pragma unroll
      for (int j = 0; j < 4; ++j) {
        int row = q0blk + qt*16 + lg*4 + j;
        int col = w*128 + dt*16 + lr;
        ob[row*512 + col] = f2bf(o[qt*8 + dt][j]);
      }
    }
  }
  if (lane < 16) {
    mpart[chunk*8192 + q0blk + w*16 + lane] = m;
    lpart[chunk*8192 + q0blk + w*16 + lane] = l;
  }
  #undef STAGE_K
}

// ---------------- combine partials (16B-vectorized opart reads) ----------------
template<int NC>
__global__ __launch_bounds__(256) void attn_combine(
    const unsigned short* __restrict__ opart, const float* __restrict__ mpart,
    const float* __restrict__ lpart, const float* __restrict__ x,
    float* __restrict__ out)
{
  int row = blockIdx.x * 4 + (threadIdx.x >> 6);
  int t = threadIdx.x & 63;
  int d0 = t * 8;
  float mc[NC], lc[NC];
  #pragma unroll
  for (int c = 0; c < NC; ++c) { mc[c] = mpart[c*8192 + row]; lc[c] = lpart[c*8192 + row]; }
  float M = mc[0];
  #pragma unroll
  for (int c = 1; c < NC; ++c) M = fmaxf(M, mc[c]);
  float wc[NC], denom = 0.f;
  #pragma unroll
  for (int c = 0; c < NC; ++c) { wc[c] = __expf(mc[c] - M); denom += wc[c] * lc[c]; }
  float inv = 1.0f / denom;
  float acc[8] = {0.f,0.f,0.f,0.f,0.f,0.f,0.f,0.f};
  const unsigned short* base = opart + (size_t)row*512 + d0;
  #pragma unroll
  for (int c = 0; c < NC; ++c) {
    int4 v = *(const int4*)(base + (size_t)c * 8192 * 512);
    const unsigned short* u = (const unsigned short*)&v;
    #pragma unroll
    for (int e = 0; e < 8; ++e) acc[e] += wc[c] * bf2f(u[e]);
  }
  float4 xv0 = *(const float4*)(x + row*512 + d0);
  float4 xv1 = *(const float4*)(x + row*512 + d0 + 4);
  float4 o0, o1;
  o0.x = xv0.x + acc[0]*inv; o0.y = xv0.y + acc[1]*inv;
  o0.z = xv0.z + acc[2]*inv; o0.w = xv0.w + acc[3]*inv;
  o1.x = xv1.x + acc[4]*inv; o1.y = xv1.y + acc[5]*inv;
  o1.z = xv1.z + acc[6]*inv; o1.w = xv1.w + acc[7]*inv;
  *(float4*)(out + row*512 + d0)     = o0;
  *(float4*)(out + row*512 + d0 + 4) = o1;
}

// ---------------- recon path (fp32 exact) ----------------
__global__ __launch_bounds__(256) void compress_pool(const float* __restrict__ fine,
    const float* __restrict__ cq, float* __restrict__ pooled, float* __restrict__ loss)
{
  if (blockIdx.x == 0 && threadIdx.x == 0) *loss = 0.f;   // fused zero (interp runs later)
  int l = blockIdx.x;
  int t = threadIdx.x;
  const float* c0 = fine + (2*l)*512;
  const float* c1 = c0 + 512;
  float q0 = cq[t], q1 = cq[t+256];
  float a0 = q0*c0[t] + q1*c0[t+256];
  float a1 = q0*c1[t] + q1*c1[t+256];
  #pragma unroll
  for (int m = 1; m < 64; m <<= 1) { a0 += __shfl_xor(a0, m); a1 += __shfl_xor(a1, m); }
  __shared__ float r0[4], r1[4];
  int w = t >> 6;
  if ((t & 63) == 0) { r0[w] = a0; r1[w] = a1; }
  __syncthreads();
  const float sc = 0.04419417382415922f;
  float g0 = (r0[0]+r0[1]+r0[2]+r0[3]) * sc;
  float g1 = (r1[0]+r1[1]+r1[2]+r1[3]) * sc;
  float mx = fmaxf(g0, g1);
  float e0 = __expf(g0-mx), e1 = __expf(g1-mx);
  float inv = 1.0f/(e0+e1);
  float w0 = e0*inv, w1 = e1*inv;
  pooled[l*512 + t]       = w0*c0[t]     + w1*c1[t];
  pooled[l*512 + t + 256] = w0*c0[t+256] + w1*c1[t+256];
}

__global__ __launch_bounds__(256) void comp_gemm(const float* __restrict__ P,
    const float* __restrict__ W, const float* __restrict__ b, float* __restrict__ out)
{
  int gid = blockIdx.x * 256 + threadIdx.x;
  int m = gid >> 9, n = gid & 511;
  const float* a = P + m * 512;
  float acc = b[n];
  #pragma unroll 8
  for (int k = 0; k < 512; ++k) acc += a[k] * W[k*512 + n];
  out[gid] = acc;
}

__global__ __launch_bounds__(256) void interp_loss(const float* __restrict__ comp,
    const float* __restrict__ fine, float* __restrict__ loss)
{
  float acc = 0.f;
  #pragma unroll
  for (int s = 0; s < 4; ++s) {
    int e = blockIdx.x*1024 + s*256 + threadIdx.x;
    int i = e >> 9, d = e & 511;
    float src = fminf(fmaxf((i + 0.5f)*0.5f - 0.5f, 0.f), 255.f);
    int i0 = (int)src;
    int i1 = min(i0 + 1, 255);
    float fr = src - (float)i0;
    float dec = (1.f - fr)*comp[i0*512 + d] + fr*comp[i1*512 + d];
    float df = dec - fine[e];
    acc += df*df;
  }
  #pragma unroll
  for (int m = 1; m < 64; m <<= 1) acc += __shfl_xor(acc, m);
  __shared__ float r[4];
  int w = threadIdx.x >> 6;
  if ((threadIdx.x & 63) == 0) r[w] = acc;
  __syncthreads();
  if (threadIdx.x == 0)
    atomicAdd(loss, (r[0]+r[1]+r[2]+r[3]) * (1.0f/262144.0f));
}

extern "C" void kernel_launch(void* const* d_in, const int* in_sizes, int n_in,
                              void* d_out, int out_size, void* d_ws, size_t ws_size,
                              hipStream_t stream) {
  const float* x     = (const float*)d_in[0];
  const float* fine  = (const float*)d_in[1];
  const float* cmem  = (const float*)d_in[2];
  const float* cq    = (const float*)d_in[3];
  const float* compW = (const float*)d_in[4];
  const float* compb = (const float*)d_in[5];
  const float* kW    = (const float*)d_in[6];
  const float* kb_   = (const float*)d_in[7];
  const float* vW    = (const float*)d_in[8];
  const float* vb_   = (const float*)d_in[9];
  const float* xkW   = (const float*)d_in[10];
  const float* xkb   = (const float*)d_in[11];
  const float* ckW   = (const float*)d_in[12];
  const float* ckb   = (const float*)d_in[13];
  const float* cvW   = (const float*)d_in[14];
  const float* cvb   = (const float*)d_in[15];

  char* ws = (char*)d_ws;
  const size_t WT = 512*512*2;              // 512 KB per transposed weight
  unsigned short* WtK  = (unsigned short*)(ws + 0*WT);
  unsigned short* WtV  = (unsigned short*)(ws + 1*WT);
  unsigned short* WtCK = (unsigned short*)(ws + 2*WT);
  unsigned short* WtCV = (unsigned short*)(ws + 3*WT);
  unsigned short* WtXK = (unsigned short*)(ws + 4*WT);
  char* base = ws + 5*WT;
  unsigned short* memk = (unsigned short*)(base);                       // 4 MB
  unsigned short* memv = (unsigned short*)(base + (4u<<20));            // 4 MB
  unsigned short* vt   = (unsigned short*)(base + (8u<<20));            // 4 MB
  unsigned short* qry  = (unsigned short*)(base + (12u<<20));           // 8 MB
  float* pooled        = (float*)(base + (20u<<20));                    // 512 KB
  float* comp          = (float*)(base + (20u<<20) + (512u<<10));       // 512 KB
  unsigned short* opart= (unsigned short*)(base + (21u<<20));           // 32 MB (NC=4)
  float* mpart         = (float*)(base + (21u<<20) + (32ull<<20));
  float* lpart         = mpart + 4*8192;

  float* out  = (float*)d_out;
  float* loss = out + 8192*512;

  wt_transpose5<<<dim3(16,16,5), 256, 0, stream>>>(kW, vW, ckW, cvW, xkW,
                                                   WtK, WtV, WtCK, WtCV, WtXK);

  proj_all<<<dim3(128,8), 256, 0, stream>>>(x, fine, cmem,
      WtXK, WtK, WtV, WtCK, WtCV,
      xkb, kb_, vb_, ckb, cvb,
      qry, memk, memv);

  v_transpose<<<dim3(128,16), 256, 0, stream>>>(memv, vt);

  attn_kernel<4><<<512, 256, 0, stream>>>(qry, memk, vt, opart, mpart, lpart);
  attn_combine<4><<<2048, 256, 0, stream>>>(opart, mpart, lpart, x, out);

  compress_pool<<<256, 256, 0, stream>>>(fine, cq, pooled, loss);
  comp_gemm<<<512, 256, 0, stream>>>(pooled, compW, compb, comp);
  interp_loss<<<256, 256, 0, stream>>>(comp, fine, loss);
}